// Round 4
// baseline (346.179 us; speedup 1.0000x reference)
//
#include <hip/hip_runtime.h>
#include <math.h>

#define BB  16
#define IDF 128
#define CDF 256
#define SL  48
#define QQ  16384   // 128*128
#define QT  64      // q-tile per block

// ws layout (floats): srcT [B][IDF][SL] | sent [B][IDF] | wsvT [IDF][IDF] (i-major)
#define WS_SRCT 0
#define WS_SENT (BB*IDF*SL)
#define WS_WSVT (WS_SENT + BB*IDF)

__global__ __launch_bounds__(256) void prep_kernel(
    const float* __restrict__ context,   // [B][CDF][SL]
    const float* __restrict__ w_ctx,     // [IDF][CDF]
    const float* __restrict__ sentence,  // [B][100]
    const float* __restrict__ w_lin,     // [IDF][100]
    const float* __restrict__ b_lin,     // [IDF]
    const float* __restrict__ w_sv,      // [IDF][IDF] (o,i)
    float* __restrict__ srcT,            // [B][IDF][SL]
    float* __restrict__ sent,            // [B][IDF]
    float* __restrict__ wsvT)            // [IDF][IDF] (i,o)
{
    const int b    = blockIdx.x;
    const int iblk = blockIdx.y;       // 0..3, 32 output rows each
    const int t    = threadIdx.x;

    __shared__ float ctx_lds[CDF * SL];   // 48 KB
    __shared__ float w_lds[32 * CDF];     // 32 KB

    {
        const float4* g4 = (const float4*)(context + b * CDF * SL);
        float4* s4 = (float4*)ctx_lds;
        #pragma unroll
        for (int r = 0; r < (CDF * SL) / 1024; ++r)
            s4[r * 256 + t] = g4[r * 256 + t];
    }
    const int i0 = iblk * 32;
    {
        const float4* g4 = (const float4*)(w_ctx + i0 * CDF);
        float4* s4 = (float4*)w_lds;
        #pragma unroll
        for (int r = 0; r < (32 * CDF) / 1024; ++r)
            s4[r * 256 + t] = g4[r * 256 + t];
    }
    __syncthreads();

    for (int r = 0; r < 6; ++r) {
        int idx = r * 256 + t;          // 0..1535
        int ii = idx / SL, s = idx % SL;
        float a0 = 0.f, a1 = 0.f, a2 = 0.f, a3 = 0.f;
        for (int c = 0; c < CDF; c += 4) {
            a0 += w_lds[ii * CDF + c + 0] * ctx_lds[(c + 0) * SL + s];
            a1 += w_lds[ii * CDF + c + 1] * ctx_lds[(c + 1) * SL + s];
            a2 += w_lds[ii * CDF + c + 2] * ctx_lds[(c + 2) * SL + s];
            a3 += w_lds[ii * CDF + c + 3] * ctx_lds[(c + 3) * SL + s];
        }
        srcT[(b * IDF + i0 + ii) * SL + s] = (a0 + a1) + (a2 + a3);
    }

    if (t < 32) {
        int o = iblk * 32 + t;
        float a = b_lin[o];
        for (int k = 0; k < 100; ++k)
            a += sentence[b * 100 + k] * w_lin[o * 100 + k];
        sent[b * IDF + o] = a;
    }

    if (b == 0) {
        for (int r = 0; r < 16; ++r) {
            int idx = iblk * 4096 + r * 256 + t;
            int i = idx >> 7, o = idx & 127;
            wsvT[idx] = w_sv[o * IDF + i];
        }
    }
}

// Fused word-attn + sentence path. Block = (b, 64-q tile). Weights via SGPR
// (block-uniform addresses), per-q data via stride-1 LDS (conflict-free).
__global__ __launch_bounds__(256, 3) void fused_kernel(
    const float* __restrict__ input,   // [B][IDF][Q]
    const float* __restrict__ srcT,    // [B][IDF][SL]
    const float* __restrict__ wsvT,    // [IDF(i)][IDF(o)]
    const float* __restrict__ sentW,   // [B][IDF]
    const int*   __restrict__ mask,    // [B][SL]
    float* __restrict__ wctx,          // out0 [B][IDF][Q]
    float* __restrict__ wsent,         // out1 [B][IDF][Q]
    float* __restrict__ wattn,         // out2 [B][SL][Q]
    float* __restrict__ satt)          // out3 [B][IDF][Q]
{
    const int bid  = blockIdx.x;          // 4096 = 16 b x 256 tiles
    const int b    = bid >> 8;
    const int q0   = (bid & 255) * QT;
    const int t    = threadIdx.x;
    const int wave = __builtin_amdgcn_readfirstlane(t >> 6);  // 0..3
    const int lane = t & 63;

    __shared__ float xs[IDF * QT];        // 32 KB  [i][q]
    __shared__ float att_lds[SL * QT];    // 12 KB  [s][q]
    __shared__ float red_m[4][QT];
    __shared__ float red_s[4][QT];
    __shared__ float sbias[SL];

    // ---- stage input tile (2048 float4, 8 per thread) ----
    {
        float4* s4 = (float4*)xs;
        #pragma unroll
        for (int r = 0; r < 8; ++r) {
            int idx = r * 256 + t;         // float4 index 0..2047
            int i = idx >> 4, c = idx & 15;
            s4[idx] = *(const float4*)(input + ((size_t)b * IDF + i) * QQ + q0 + c * 4);
        }
    }
    if (t < SL) sbias[t] = mask[b * SL + t] ? -INFINITY : 0.f;
    __syncthreads();

    const float* sT = srcT + b * IDF * SL;     // block-uniform base

    //======== PHASE B: logits (wave owns 12 s) + softmax ========
    const int s0 = wave * 12;
    float l[12];
    #pragma unroll
    for (int j = 0; j < 12; ++j) l[j] = 0.f;

    #pragma unroll 4
    for (int i = 0; i < IDF; ++i) {
        float v = xs[i * QT + lane];
        const float4* r4 = (const float4*)(sT + i * SL + s0);  // uniform -> s_load
        float4 w0 = r4[0], w1 = r4[1], w2 = r4[2];
        l[0]  += v * w0.x;  l[1]  += v * w0.y;  l[2]  += v * w0.z;  l[3]  += v * w0.w;
        l[4]  += v * w1.x;  l[5]  += v * w1.y;  l[6]  += v * w1.z;  l[7]  += v * w1.w;
        l[8]  += v * w2.x;  l[9]  += v * w2.y;  l[10] += v * w2.z;  l[11] += v * w2.w;
    }

    float mloc = -INFINITY;
    #pragma unroll
    for (int j = 0; j < 12; ++j) {
        l[j] += sbias[s0 + j];
        mloc = fmaxf(mloc, l[j]);
    }
    red_m[wave][lane] = mloc;
    __syncthreads();
    float mq = fmaxf(fmaxf(red_m[0][lane], red_m[1][lane]),
                     fmaxf(red_m[2][lane], red_m[3][lane]));
    float sloc = 0.f;
    #pragma unroll
    for (int j = 0; j < 12; ++j) { l[j] = __expf(l[j] - mq); sloc += l[j]; }
    red_s[wave][lane] = sloc;
    __syncthreads();
    float tot = (red_s[0][lane] + red_s[1][lane]) + (red_s[2][lane] + red_s[3][lane]);
    float inv = 1.f / tot;
    #pragma unroll
    for (int j = 0; j < 12; ++j) {
        float a = l[j] * inv;
        wattn[((size_t)b * SL + s0 + j) * QQ + q0 + lane] = a;
        att_lds[(s0 + j) * QT + lane] = a;
    }
    __syncthreads();   // att_lds ready; red_* free for reuse

    //======== PHASE C: wctx (wave owns 32 i) ========
    {
        float att[SL];
        #pragma unroll
        for (int s = 0; s < SL; ++s) att[s] = att_lds[s * QT + lane];
        const int i0 = wave * 32;
        #pragma unroll 2
        for (int ii = 0; ii < 32; ++ii) {
            int i = i0 + ii;
            const float4* r4 = (const float4*)(sT + i * SL);   // uniform -> s_load
            float p0 = 0.f, p1 = 0.f, p2 = 0.f, p3 = 0.f;
            #pragma unroll
            for (int jj = 0; jj < 12; ++jj) {
                float4 w = r4[jj];
                p0 += w.x * att[jj * 4 + 0];
                p1 += w.y * att[jj * 4 + 1];
                p2 += w.z * att[jj * 4 + 2];
                p3 += w.w * att[jj * 4 + 3];
            }
            wctx[((size_t)b * IDF + i) * QQ + q0 + lane] = (p0 + p1) + (p2 + p3);
        }
    }

    //======== PHASE A: sentence path (wave owns 32 channels) ========
    {
        const float* wv = wsvT + wave * 32;       // uniform
        const float* sw = sentW + b * IDF;        // uniform
        float acc[32];
        #pragma unroll
        for (int oo = 0; oo < 32; ++oo) acc[oo] = 0.f;

        #pragma unroll 2
        for (int i = 0; i < IDF; ++i) {
            float v = xs[i * QT + lane] * sw[i];
            const float4* r4 = (const float4*)(wv + i * IDF); // uniform -> s_load
            #pragma unroll
            for (int jj = 0; jj < 8; ++jj) {
                float4 w = r4[jj];
                acc[jj * 4 + 0] += w.x * v;
                acc[jj * 4 + 1] += w.y * v;
                acc[jj * 4 + 2] += w.z * v;
                acc[jj * 4 + 3] += w.w * v;
            }
        }

        float lmax = -INFINITY;
        #pragma unroll
        for (int oo = 0; oo < 32; ++oo) lmax = fmaxf(lmax, acc[oo]);
        red_m[wave][lane] = lmax;
        __syncthreads();
        float mc = fmaxf(fmaxf(red_m[0][lane], red_m[1][lane]),
                         fmaxf(red_m[2][lane], red_m[3][lane]));
        float lsum = 0.f;
        #pragma unroll
        for (int oo = 0; oo < 32; ++oo) { acc[oo] = __expf(acc[oo] - mc); lsum += acc[oo]; }
        red_s[wave][lane] = lsum;
        __syncthreads();
        float ctot = (red_s[0][lane] + red_s[1][lane]) + (red_s[2][lane] + red_s[3][lane]);
        float cinv = 1.f / ctot;

        #pragma unroll
        for (int oo = 0; oo < 32; ++oo) {
            int o = wave * 32 + oo;
            float p = acc[oo] * cinv;
            size_t off = ((size_t)b * IDF + o) * QQ + q0 + lane;
            satt[off]  = p;
            wsent[off] = sw[o] * p;
        }
    }
}

extern "C" void kernel_launch(void* const* d_in, const int* in_sizes, int n_in,
                              void* d_out, int out_size, void* d_ws, size_t ws_size,
                              hipStream_t stream) {
    const float* input    = (const float*)d_in[0];
    const float* sentence = (const float*)d_in[1];
    const float* context  = (const float*)d_in[2];
    const int*   mask     = (const int*)d_in[3];
    const float* w_ctx    = (const float*)d_in[4];
    const float* w_sv     = (const float*)d_in[5];
    const float* w_lin    = (const float*)d_in[6];
    const float* b_lin    = (const float*)d_in[7];

    float* out = (float*)d_out;
    float* out_wctx  = out;                                   // [B][IDF][Q]
    float* out_wsent = out + (size_t)BB * IDF * QQ;           // [B][IDF][Q]
    float* out_wattn = out + 2 * (size_t)BB * IDF * QQ;       // [B][SL][Q]
    float* out_satt  = out_wattn + (size_t)BB * SL * QQ;      // [B][IDF][Q]

    float* ws   = (float*)d_ws;
    float* srcT = ws + WS_SRCT;
    float* sent = ws + WS_SENT;
    float* wsvT = ws + WS_WSVT;

    prep_kernel<<<dim3(16, 4), 256, 0, stream>>>(context, w_ctx, sentence,
                                                 w_lin, b_lin, w_sv,
                                                 srcT, sent, wsvT);
    fused_kernel<<<dim3(4096), 256, 0, stream>>>(input, srcT, wsvT, sent, mask,
                                                 out_wctx, out_wsent,
                                                 out_wattn, out_satt);
}